// Round 2
// baseline (561.919 us; speedup 1.0000x reference)
//
#include <hip/hip_runtime.h>
#include <hip/hip_bf16.h>
#include <math.h>

#define BB 2
#define MM 8192
#define NN (BB * MM)
#define CHUNK 512   // candidates per wave (16 waves/block)

// ws layout:
#define ACC_OFF  0
#define RANK_OFF 64
#define IDX_OFF  65600
#define PK_OFF   1114176

__global__ void prep_kernel(const float* __restrict__ coords, float4* __restrict__ pk) {
    int i = blockIdx.x * blockDim.x + threadIdx.x;
    if (i < NN) {
        float x = coords[3 * i], y = coords[3 * i + 1], z = coords[3 * i + 2];
        // MUST match dot ordering in knn_kernel so self-distance is exactly 0.
        float sq = fmaf(x, x, fmaf(y, y, z * z));
        pk[i] = make_float4(x, y, z, sq);
    }
}

// 256 blocks x 1024 threads (16 waves). Block handles 64 queries (one per lane);
// wave w scans candidates [w*512, (w+1)*512) of the cloud. 4 waves/SIMD hides
// the scalar-load latency that killed round 1 (1 wave/SIMD, 28% VALUBusy).
__global__ __launch_bounds__(1024) void knn_kernel(const float* __restrict__ scores,
                                                   const float4* __restrict__ pk,
                                                   int* __restrict__ out_idx,
                                                   int* __restrict__ out_rank) {
    __shared__ unsigned lds_k[16][16][64];  // [wave][slot][query-lane] : lane-consecutive, conflict-free
    __shared__ int lds_r[16][64];

    const int tid  = threadIdx.x;
    const int lane = tid & 63;
    const int wv   = __builtin_amdgcn_readfirstlane(tid >> 6);
    const int qbase = blockIdx.x * 64;
    const int cbase = (qbase >> 13) << 13;  // cloud base (uniform -> scalar loads)
    const int q = qbase + lane;

    float4 p = pk[q];
    float  s = scores[q];

    // top-16 packed keys: (order-transformed d2 & ~0x1FFF) | local_j (13 bits)
    unsigned slot[16];
#pragma unroll
    for (int k = 0; k < 16; ++k) slot[k] = 0xFFFF0000u + (unsigned)k;
    unsigned thr = 0xFFFF000Fu;
    int rank = 0;

    auto proc = [&](float4 c, float sc, int j) {
        float dot = fmaf(p.x, c.x, fmaf(p.y, c.y, p.z * c.z));
        float d2  = fmaf(-2.0f, dot, p.w + c.w);   // exactly 0 for self
        rank += (sc < s) ? 1 : 0;
        unsigned u = __float_as_uint(d2);
        unsigned ord = u ^ (0x80000000u | (unsigned)((int)u >> 31));
        unsigned key = (ord & 0xFFFFE000u) | (unsigned)j;
        if (key < thr) {  // exec-masked: wave pays only on some-lane-insert
#pragma unroll
            for (int k = 0; k < 16; ++k) slot[k] = (slot[k] == thr) ? key : slot[k];
            unsigned m = slot[0];
#pragma unroll
            for (int k = 1; k < 16; ++k) m = max(m, slot[k]);
            thr = m;
        }
    };

    const int j0 = wv * CHUNK;
    // group-of-4 scalar prefetch: SGPR loads are exec-independent, hoist past inserts
    float4 c0 = pk[cbase + j0 + 0], c1 = pk[cbase + j0 + 1];
    float4 c2 = pk[cbase + j0 + 2], c3 = pk[cbase + j0 + 3];
    float  t0 = scores[cbase + j0 + 0], t1 = scores[cbase + j0 + 1];
    float  t2 = scores[cbase + j0 + 2], t3 = scores[cbase + j0 + 3];
    for (int jj = 0; jj < CHUNK; jj += 4) {
        float4 n0, n1, n2, n3; float u0, u1, u2, u3;
        if (jj + 4 < CHUNK) {  // uniform branch
            int nj = cbase + j0 + jj + 4;
            n0 = pk[nj + 0]; n1 = pk[nj + 1]; n2 = pk[nj + 2]; n3 = pk[nj + 3];
            u0 = scores[nj + 0]; u1 = scores[nj + 1]; u2 = scores[nj + 2]; u3 = scores[nj + 3];
        }
        proc(c0, t0, j0 + jj + 0);
        proc(c1, t1, j0 + jj + 1);
        proc(c2, t2, j0 + jj + 2);
        proc(c3, t3, j0 + jj + 3);
        c0 = n0; c1 = n1; c2 = n2; c3 = n3;
        t0 = u0; t1 = u1; t2 = u2; t3 = u3;
    }

    // Batcher odd-even mergesort of 16 keys, ascending
#pragma unroll
    for (int p2 = 1; p2 < 16; p2 <<= 1) {
#pragma unroll
        for (int k2 = p2; k2 >= 1; k2 >>= 1) {
#pragma unroll
            for (int j2 = k2 % p2; j2 + k2 < 16; j2 += 2 * k2) {
#pragma unroll
                for (int i2 = 0; i2 < k2; ++i2) {
                    if (i2 + j2 + k2 < 16) {
                        if (((i2 + j2) / (2 * p2)) == ((i2 + j2 + k2) / (2 * p2))) {
                            unsigned a = slot[i2 + j2], b = slot[i2 + j2 + k2];
                            slot[i2 + j2]      = min(a, b);
                            slot[i2 + j2 + k2] = max(a, b);
                        }
                    }
                }
            }
        }
    }

#pragma unroll
    for (int k = 0; k < 16; ++k) lds_k[wv][k][lane] = slot[k];
    lds_r[wv][lane] = rank;

    // tree merge 16 -> 1 sorted lists: truncated bitonic merge, register-only
    for (int half = 8; half >= 1; half >>= 1) {
        __syncthreads();
        if (wv < half) {
            unsigned a[16], b[16], m[16];
#pragma unroll
            for (int k = 0; k < 16; ++k) a[k] = lds_k[wv][k][lane];
#pragma unroll
            for (int k = 0; k < 16; ++k) b[k] = lds_k[wv + half][k][lane];
#pragma unroll
            for (int k = 0; k < 16; ++k) m[k] = min(a[k], b[15 - k]);  // smallest-16 (bitonic)
#pragma unroll
            for (int st = 8; st >= 1; st >>= 1) {
#pragma unroll
                for (int i = 0; i < 16; ++i) {
                    if ((i & st) == 0) {
                        unsigned lo = min(m[i], m[i + st]);
                        unsigned hi = max(m[i], m[i + st]);
                        m[i] = lo; m[i + st] = hi;
                    }
                }
            }
#pragma unroll
            for (int k = 0; k < 16; ++k) lds_k[wv][k][lane] = m[k];
        }
    }
    __syncthreads();

    if (wv == 0) {
        int rsum = 0;
#pragma unroll
        for (int w = 0; w < 16; ++w) rsum += lds_r[w][lane];
        out_rank[qbase + lane] = rsum;
#pragma unroll
        for (int k = 0; k < 16; ++k)
            out_idx[(qbase + lane) * 16 + k] = (int)(lds_k[0][k][lane] & 0x1FFFu) + cbase;
    }
}

// one thread per (query, k) pair: 16384*16 threads
__global__ __launch_bounds__(256) void loss_kernel(const float* __restrict__ scores,
                                                   const float* __restrict__ coords,
                                                   const int* __restrict__ knn,
                                                   const int* __restrict__ rank,
                                                   float* __restrict__ acc) {
    const int t = blockIdx.x * 256 + threadIdx.x;
    const int q = t >> 4, k = t & 15;
    const int nb = knn[t];                 // coalesced
    const float s  = scores[q];
    const float sn = scores[nb];
    const float diff = fabsf(s - sn);
    const float sim = 1.0f - diff;
    const float sg = 1.0f / (1.0f + expf(-2.0f * sim));  // sigmoid(sim/0.5)

    float a_wd = 0.f, a_w = 0.f, a_pos = 0.f, a_neg = 0.f, snk = 0.f;
    if (k < 8) {
        float cx = coords[3 * q],  cy = coords[3 * q + 1],  cz = coords[3 * q + 2];
        float nx = coords[3 * nb], ny = coords[3 * nb + 1], nz = coords[3 * nb + 2];
        float dx = cx - nx, dy = cy - ny, dz = cz - nz;
        float d = sqrtf(dx * dx + dy * dy + dz * dz);
        float w = expf(-10.0f * d);
        a_wd = w * diff * diff;
        a_w  = w;
        a_pos = logf(sg + 1e-8f);
        snk = sn;
    } else {
        a_neg = logf(1.0f - sg + 1e-8f);
    }

    // sum of the 8 near-neighbor scores within the 16-lane query group
    float nsum = snk;
#pragma unroll
    for (int off = 1; off < 16; off <<= 1) nsum += __shfl_xor(nsum, off);

    float a_sm = 0.f, a_di = 0.f;
    if (k == 0) {
        float t1 = s - nsum * 0.125f;
        a_sm = t1 * t1;
        float t2 = s - (float)rank[q] * (1.0f / 8191.0f);
        a_di = t2 * t2;
    }

#pragma unroll
    for (int off = 1; off < 64; off <<= 1) {
        a_wd  += __shfl_xor(a_wd, off);
        a_w   += __shfl_xor(a_w, off);
        a_pos += __shfl_xor(a_pos, off);
        a_neg += __shfl_xor(a_neg, off);
        a_sm  += __shfl_xor(a_sm, off);
        a_di  += __shfl_xor(a_di, off);
    }
    if ((threadIdx.x & 63) == 0) {
        atomicAdd(&acc[0], a_wd);
        atomicAdd(&acc[1], a_w);
        atomicAdd(&acc[2], a_pos);
        atomicAdd(&acc[3], a_neg);
        atomicAdd(&acc[4], a_sm);
        atomicAdd(&acc[5], a_di);
    }
}

__global__ void fin_kernel(const float* __restrict__ acc, float* __restrict__ out) {
    if (threadIdx.x == 0) {
        float l_loc = acc[0] / fmaxf(acc[1], 1e-8f);
        float l_pos = -acc[2] / (float)(NN * 8);
        float l_neg = -acc[3] / (float)(NN * 8);
        float l_sm  = acc[4] / (float)NN;
        float l_di  = acc[5] / (float)NN;
        out[0] = l_loc + 0.5f * (l_pos + l_neg) + 0.3f * l_di + 0.2f * l_sm;
    }
}

extern "C" void kernel_launch(void* const* d_in, const int* in_sizes, int n_in,
                              void* d_out, int out_size, void* d_ws, size_t ws_size,
                              hipStream_t stream) {
    const float* scores = (const float*)d_in[0];
    const float* coords = (const float*)d_in[1];
    (void)in_sizes; (void)n_in; (void)out_size; (void)ws_size;

    char* ws = (char*)d_ws;
    float*  acc  = (float*)(ws + ACC_OFF);
    int*    rank = (int*)(ws + RANK_OFF);
    int*    knn  = (int*)(ws + IDX_OFF);
    float4* pk   = (float4*)(ws + PK_OFF);
    float*  out  = (float*)d_out;

    hipMemsetAsync(acc, 0, 64, stream);
    prep_kernel<<<64, 256, 0, stream>>>(coords, pk);
    knn_kernel<<<256, 1024, 0, stream>>>(scores, pk, knn, rank);
    loss_kernel<<<NN * 16 / 256, 256, 0, stream>>>(scores, coords, knn, rank, acc);
    fin_kernel<<<1, 64, 0, stream>>>(acc, out);
}

// Round 3
// 159.268 us; speedup vs baseline: 3.5281x; 3.5281x over previous
//
#include <hip/hip_runtime.h>
#include <hip/hip_bf16.h>
#include <math.h>

#define BB 2
#define MM 8192
#define NN (BB * MM)
#define CHUNK 512        // candidates per wave (16 waves/block)
#define LOSS_BLOCKS 1024

// ws layout:
#define PART_OFF 0        // 6 * LOSS_BLOCKS floats = 24576 B
#define RANK_OFF 24576    // 4 * NN = 65536 B
#define IDX_OFF  90112    // 16 * 4 * NN = 1048576 B
#define PK_OFF   1138688  // 16 * NN = 262144 B

__global__ void prep_kernel(const float* __restrict__ coords, float4* __restrict__ pk) {
    int i = blockIdx.x * blockDim.x + threadIdx.x;
    if (i < NN) {
        float x = coords[3 * i], y = coords[3 * i + 1], z = coords[3 * i + 2];
        // MUST match dot ordering in knn_kernel so self-distance is exactly 0.
        float sq = fmaf(x, x, fmaf(y, y, z * z));
        pk[i] = make_float4(x, y, z, sq);
    }
}

// 256 blocks x 1024 threads (16 waves). Block handles 64 queries (one per lane);
// wave w scans candidates [w*512, (w+1)*512). Fully branchless top-16
// maintenance: batches of 16 keys -> Batcher sort (63 CE) -> truncated bitonic
// merge with running sorted-16 (16 min + 32 CE). ~13 ops/cand amortized, no
// divergence, loads pipeline freely.
__global__ __launch_bounds__(1024) void knn_kernel(const float* __restrict__ scores,
                                                   const float4* __restrict__ pk,
                                                   int* __restrict__ out_idx,
                                                   int* __restrict__ out_rank) {
    __shared__ unsigned lds_k[16][16][64];  // [wave][slot][query-lane]: conflict-free
    __shared__ int lds_r[16][64];

    const int tid  = threadIdx.x;
    const int lane = tid & 63;
    const int wv   = __builtin_amdgcn_readfirstlane(tid >> 6);
    const int qbase = blockIdx.x * 64;
    const int cbase = (qbase >> 13) << 13;  // cloud base (uniform)
    const int q = qbase + lane;

    const float4 p = pk[q];
    const float  s = scores[q];
    const float4* __restrict__ pkc = pk + cbase;
    const float*  __restrict__ scc = scores + cbase;

    // running top-16, sorted ascending; keys = (d2 bits & ~0x1FFF) | local_j
    unsigned slot[16];
#pragma unroll
    for (int k = 0; k < 16; ++k) slot[k] = 0xFFFF0000u + (unsigned)k;
    int rank = 0;

    const int j0 = wv * CHUNK;
    for (int jj = 0; jj < CHUNK; jj += 16) {
        unsigned kb[16];
#pragma unroll
        for (int i = 0; i < 16; ++i) {
            const int j = j0 + jj + i;          // uniform -> scalar loads
            const float4 c = pkc[j];
            const float  sc = scc[j];
            float dot = fmaf(p.x, c.x, fmaf(p.y, c.y, p.z * c.z));
            float d2  = fmaf(-2.0f, dot, p.w + c.w);   // exactly 0 for self; >=0 otherwise
            rank += (sc < s) ? 1 : 0;
            kb[i] = (__float_as_uint(d2) & 0xFFFFE000u) | (unsigned)j;
        }
        // Batcher odd-even mergesort of kb, ascending (63 CE)
#pragma unroll
        for (int p2 = 1; p2 < 16; p2 <<= 1) {
#pragma unroll
            for (int k2 = p2; k2 >= 1; k2 >>= 1) {
#pragma unroll
                for (int j2 = k2 % p2; j2 + k2 < 16; j2 += 2 * k2) {
#pragma unroll
                    for (int i2 = 0; i2 < k2; ++i2) {
                        if (i2 + j2 + k2 < 16) {
                            if (((i2 + j2) / (2 * p2)) == ((i2 + j2 + k2) / (2 * p2))) {
                                unsigned a = kb[i2 + j2], b = kb[i2 + j2 + k2];
                                kb[i2 + j2]      = min(a, b);
                                kb[i2 + j2 + k2] = max(a, b);
                            }
                        }
                    }
                }
            }
        }
        // truncated bitonic merge: lowest 16 of (slot ∪ kb), back to sorted
        unsigned m[16];
#pragma unroll
        for (int k = 0; k < 16; ++k) m[k] = min(slot[k], kb[15 - k]);
#pragma unroll
        for (int st = 8; st >= 1; st >>= 1) {
#pragma unroll
            for (int i = 0; i < 16; ++i) {
                if ((i & st) == 0) {
                    unsigned lo = min(m[i], m[i + st]);
                    unsigned hi = max(m[i], m[i + st]);
                    m[i] = lo; m[i + st] = hi;
                }
            }
        }
#pragma unroll
        for (int k = 0; k < 16; ++k) slot[k] = m[k];
    }

#pragma unroll
    for (int k = 0; k < 16; ++k) lds_k[wv][k][lane] = slot[k];
    lds_r[wv][lane] = rank;

    // tree merge 16 -> 1 sorted lists (truncated bitonic, register-only)
    for (int half = 8; half >= 1; half >>= 1) {
        __syncthreads();
        if (wv < half) {
            unsigned a[16], m[16];
#pragma unroll
            for (int k = 0; k < 16; ++k) a[k] = lds_k[wv][k][lane];
#pragma unroll
            for (int k = 0; k < 16; ++k) m[k] = min(a[k], lds_k[wv + half][15 - k][lane]);
#pragma unroll
            for (int st = 8; st >= 1; st >>= 1) {
#pragma unroll
                for (int i = 0; i < 16; ++i) {
                    if ((i & st) == 0) {
                        unsigned lo = min(m[i], m[i + st]);
                        unsigned hi = max(m[i], m[i + st]);
                        m[i] = lo; m[i + st] = hi;
                    }
                }
            }
#pragma unroll
            for (int k = 0; k < 16; ++k) lds_k[wv][k][lane] = m[k];
        }
    }
    __syncthreads();

    if (wv == 0) {
        int rsum = 0;
#pragma unroll
        for (int w = 0; w < 16; ++w) rsum += lds_r[w][lane];
        out_rank[qbase + lane] = rsum;
#pragma unroll
        for (int k = 0; k < 16; ++k)
            out_idx[(qbase + lane) * 16 + k] = (int)(lds_k[0][k][lane] & 0x1FFFu) + cbase;
    }
}

// one thread per (query, k) pair; NO global atomics: per-block partials to ws.
__global__ __launch_bounds__(256) void loss_kernel(const float* __restrict__ scores,
                                                   const float* __restrict__ coords,
                                                   const int* __restrict__ knn,
                                                   const int* __restrict__ rank,
                                                   float* __restrict__ partial) {
    __shared__ float red[4][6];
    const int t = blockIdx.x * 256 + threadIdx.x;
    const int q = t >> 4, k = t & 15;
    const int nb = knn[t];                 // coalesced
    const float s  = scores[q];
    const float sn = scores[nb];
    const float diff = fabsf(s - sn);
    const float sim = 1.0f - diff;
    const float sg = 1.0f / (1.0f + expf(-2.0f * sim));  // sigmoid(sim/0.5)

    float a_wd = 0.f, a_w = 0.f, a_pos = 0.f, a_neg = 0.f, snk = 0.f;
    if (k < 8) {
        float cx = coords[3 * q],  cy = coords[3 * q + 1],  cz = coords[3 * q + 2];
        float nx = coords[3 * nb], ny = coords[3 * nb + 1], nz = coords[3 * nb + 2];
        float dx = cx - nx, dy = cy - ny, dz = cz - nz;
        float d = sqrtf(dx * dx + dy * dy + dz * dz);
        float w = expf(-10.0f * d);
        a_wd = w * diff * diff;
        a_w  = w;
        a_pos = logf(sg + 1e-8f);
        snk = sn;
    } else {
        a_neg = logf(1.0f - sg + 1e-8f);
    }

    float nsum = snk;
#pragma unroll
    for (int off = 1; off < 16; off <<= 1) nsum += __shfl_xor(nsum, off);

    float a_sm = 0.f, a_di = 0.f;
    if (k == 0) {
        float t1 = s - nsum * 0.125f;
        a_sm = t1 * t1;
        float t2 = s - (float)rank[q] * (1.0f / 8191.0f);
        a_di = t2 * t2;
    }

#pragma unroll
    for (int off = 1; off < 64; off <<= 1) {
        a_wd  += __shfl_xor(a_wd, off);
        a_w   += __shfl_xor(a_w, off);
        a_pos += __shfl_xor(a_pos, off);
        a_neg += __shfl_xor(a_neg, off);
        a_sm  += __shfl_xor(a_sm, off);
        a_di  += __shfl_xor(a_di, off);
    }
    const int wv = threadIdx.x >> 6;
    if ((threadIdx.x & 63) == 0) {
        red[wv][0] = a_wd; red[wv][1] = a_w; red[wv][2] = a_pos;
        red[wv][3] = a_neg; red[wv][4] = a_sm; red[wv][5] = a_di;
    }
    __syncthreads();
    if (threadIdx.x < 6) {
        float v = red[0][threadIdx.x] + red[1][threadIdx.x] +
                  red[2][threadIdx.x] + red[3][threadIdx.x];
        partial[threadIdx.x * LOSS_BLOCKS + blockIdx.x] = v;
    }
}

__global__ __launch_bounds__(1024) void fin_kernel(const float* __restrict__ partial,
                                                   float* __restrict__ out) {
    __shared__ float red[16][6];
    const int tid = threadIdx.x;
    float a[6];
#pragma unroll
    for (int term = 0; term < 6; ++term) a[term] = partial[term * LOSS_BLOCKS + tid];
#pragma unroll
    for (int off = 1; off < 64; off <<= 1) {
#pragma unroll
        for (int term = 0; term < 6; ++term) a[term] += __shfl_xor(a[term], off);
    }
    if ((tid & 63) == 0) {
#pragma unroll
        for (int term = 0; term < 6; ++term) red[tid >> 6][term] = a[term];
    }
    __syncthreads();
    if (tid == 0) {
        float acc[6];
#pragma unroll
        for (int term = 0; term < 6; ++term) {
            float v = 0.f;
#pragma unroll
            for (int w = 0; w < 16; ++w) v += red[w][term];
            acc[term] = v;
        }
        float l_loc = acc[0] / fmaxf(acc[1], 1e-8f);
        float l_pos = -acc[2] / (float)(NN * 8);
        float l_neg = -acc[3] / (float)(NN * 8);
        float l_sm  = acc[4] / (float)NN;
        float l_di  = acc[5] / (float)NN;
        out[0] = l_loc + 0.5f * (l_pos + l_neg) + 0.3f * l_di + 0.2f * l_sm;
    }
}

extern "C" void kernel_launch(void* const* d_in, const int* in_sizes, int n_in,
                              void* d_out, int out_size, void* d_ws, size_t ws_size,
                              hipStream_t stream) {
    const float* scores = (const float*)d_in[0];
    const float* coords = (const float*)d_in[1];
    (void)in_sizes; (void)n_in; (void)out_size; (void)ws_size;

    char* ws = (char*)d_ws;
    float*  part = (float*)(ws + PART_OFF);
    int*    rank = (int*)(ws + RANK_OFF);
    int*    knn  = (int*)(ws + IDX_OFF);
    float4* pk   = (float4*)(ws + PK_OFF);
    float*  out  = (float*)d_out;

    prep_kernel<<<64, 256, 0, stream>>>(coords, pk);
    knn_kernel<<<256, 1024, 0, stream>>>(scores, pk, knn, rank);
    loss_kernel<<<LOSS_BLOCKS, 256, 0, stream>>>(scores, coords, knn, rank, part);
    fin_kernel<<<1, 1024, 0, stream>>>(part, out);
}

// Round 4
// 154.890 us; speedup vs baseline: 3.6279x; 1.0283x over previous
//
#include <hip/hip_runtime.h>
#include <hip/hip_bf16.h>
#include <math.h>

#define BB 2
#define MM 8192
#define NN (BB * MM)
#define NBATCH (NN / 16)      // 1024 batches of 16 sorted points
#define NCELL 4096            // 16^3 morton cells per cloud
#define LOSS_BLOCKS 1024

// ws layout (bytes):
#define PART_OFF   0          // 6 * LOSS_BLOCKS floats = 24576
#define RANK_OFF   24576      // NN ints = 65536
#define IDX_OFF    90112      // NN*16 ints = 1048576
#define PK_OFF     1138688    // NN float4 = 262144
#define SS_OFF     1400832    // NN floats = 65536
#define CELLID_OFF 1466368    // NN ints = 65536
#define CNT_OFF    1531904    // 2*NCELL ints = 32768
#define CUR_OFF    1564672    // 2*NCELL ints = 32768
#define BBLO_OFF   1597440    // NBATCH float4 = 16384
#define BBHI_OFF   1613824    // NBATCH float4 = 16384

__device__ __forceinline__ unsigned mort3(unsigned x, unsigned y, unsigned z) {
    unsigned m = 0;
#pragma unroll
    for (int i = 0; i < 4; ++i) {
        m |= ((x >> i) & 1u) << (3 * i);
        m |= ((y >> i) & 1u) << (3 * i + 1);
        m |= ((z >> i) & 1u) << (3 * i + 2);
    }
    return m;
}

__global__ void count_kernel(const float* __restrict__ coords, int* __restrict__ cellid,
                             int* __restrict__ cnt) {
    int i = blockIdx.x * 256 + threadIdx.x;
    if (i < NN) {
        float x = coords[3 * i], y = coords[3 * i + 1], z = coords[3 * i + 2];
        int cx = min(15, max(0, (int)floorf(x) + 8));
        int cy = min(15, max(0, (int)floorf(y) + 8));
        int cz = min(15, max(0, (int)floorf(z) + 8));
        int cid = (i >> 13) * NCELL + (int)mort3((unsigned)cx, (unsigned)cy, (unsigned)cz);
        cellid[i] = cid;
        atomicAdd(&cnt[cid], 1);
    }
}

// exclusive prefix over 8192 cell counts -> cursor (scatter start positions)
__global__ __launch_bounds__(1024) void scan_kernel(const int* __restrict__ cnt,
                                                    int* __restrict__ cursor) {
    __shared__ int wsum[16];
    const int tid = threadIdx.x, lane = tid & 63, wv = tid >> 6;
    int v[8]; int run = 0;
#pragma unroll
    for (int i = 0; i < 8; ++i) { int t = cnt[tid * 8 + i]; v[i] = run; run += t; }
    int inc = run;
#pragma unroll
    for (int off = 1; off < 64; off <<= 1) {
        int y = __shfl_up(inc, off);
        if (lane >= off) inc += y;
    }
    int laneExcl = inc - run;
    if (lane == 63) wsum[wv] = inc;
    __syncthreads();
    int wbase = 0;
#pragma unroll
    for (int w = 0; w < 16; ++w) wbase += (w < wv) ? wsum[w] : 0;
    const int base = wbase + laneExcl;
#pragma unroll
    for (int i = 0; i < 8; ++i) cursor[tid * 8 + i] = base + v[i];
}

__global__ void scatter_kernel(const float* __restrict__ coords, const float* __restrict__ scores,
                               const int* __restrict__ cellid, int* __restrict__ cursor,
                               float4* __restrict__ pk_s, float* __restrict__ s_s) {
    int i = blockIdx.x * 256 + threadIdx.x;
    if (i < NN) {
        int pos = atomicAdd(&cursor[cellid[i]], 1);
        float x = coords[3 * i], y = coords[3 * i + 1], z = coords[3 * i + 2];
        // MUST match dot ordering in knn_kernel so self-distance is exactly 0.
        float sq = fmaf(x, x, fmaf(y, y, z * z));
        pk_s[pos] = make_float4(x, y, z, sq);
        s_s[pos] = scores[i];
    }
}

__global__ void bbox_kernel(const float4* __restrict__ pk_s, float4* __restrict__ bb_lo,
                            float4* __restrict__ bb_hi) {
    int b = blockIdx.x * 256 + threadIdx.x;
    if (b < NBATCH) {
        float4 c = pk_s[b * 16];
        float lx = c.x, ly = c.y, lz = c.z, hx = c.x, hy = c.y, hz = c.z;
#pragma unroll
        for (int i = 1; i < 16; ++i) {
            c = pk_s[b * 16 + i];
            lx = fminf(lx, c.x); ly = fminf(ly, c.y); lz = fminf(lz, c.z);
            hx = fmaxf(hx, c.x); hy = fmaxf(hy, c.y); hz = fmaxf(hz, c.z);
        }
        bb_lo[b] = make_float4(lx, ly, lz, 0.f);
        bb_hi[b] = make_float4(hx, hy, hz, 0.f);
    }
}

__device__ __forceinline__ void sort16(unsigned (&a)[16]) {
    // Batcher odd-even mergesort, ascending (verified in R3, absmax 0)
#pragma unroll
    for (int p2 = 1; p2 < 16; p2 <<= 1) {
#pragma unroll
        for (int k2 = p2; k2 >= 1; k2 >>= 1) {
#pragma unroll
            for (int j2 = k2 % p2; j2 + k2 < 16; j2 += 2 * k2) {
#pragma unroll
                for (int i2 = 0; i2 < k2; ++i2) {
                    if (i2 + j2 + k2 < 16) {
                        if (((i2 + j2) / (2 * p2)) == ((i2 + j2 + k2) / (2 * p2))) {
                            unsigned x = a[i2 + j2], y = a[i2 + j2 + k2];
                            a[i2 + j2]      = min(x, y);
                            a[i2 + j2 + k2] = max(x, y);
                        }
                    }
                }
            }
        }
    }
}

__device__ __forceinline__ void truncmerge(unsigned (&slot)[16], const unsigned (&kb)[16]) {
    // lowest-16 of (sorted slot ∪ sorted kb), result sorted (verified in R3)
    unsigned m[16];
#pragma unroll
    for (int k = 0; k < 16; ++k) m[k] = min(slot[k], kb[15 - k]);
#pragma unroll
    for (int st = 8; st >= 1; st >>= 1) {
#pragma unroll
        for (int i = 0; i < 16; ++i) {
            if ((i & st) == 0) {
                unsigned lo = min(m[i], m[i + st]);
                unsigned hi = max(m[i], m[i + st]);
                m[i] = lo; m[i + st] = hi;
            }
        }
    }
#pragma unroll
    for (int k = 0; k < 16; ++k) slot[k] = m[k];
}

// 256 blocks x 1024 threads; block = 64 Morton-consecutive sorted queries.
// Wave w scans batches {w, w+16, ...} with bbox lower-bound pruning; exact.
__global__ __launch_bounds__(1024) void knn_kernel(const float4* __restrict__ pk_s,
                                                   const float4* __restrict__ bb_lo,
                                                   const float4* __restrict__ bb_hi,
                                                   int* __restrict__ out_idx) {
    __shared__ unsigned lds_k[16][16][64];
    const int tid = threadIdx.x, lane = tid & 63;
    const int wv = __builtin_amdgcn_readfirstlane(tid >> 6);
    const int qbase = blockIdx.x * 64;
    const int cloudbase = (qbase >> 13) << 13;
    const int q = qbase + lane;
    const float4 p = pk_s[q];
    const int sb0 = (qbase - cloudbase) >> 4;      // uniform seed batch (multiple of 4)
    const float4* __restrict__ pc = pk_s + cloudbase;
    const int bbase = cloudbase >> 4;

    unsigned slot[16];
#pragma unroll
    for (int k = 0; k < 16; ++k) slot[k] = 0x7F000000u + (unsigned)k;  // > any real key
    float t_f = 3.0e38f;

    auto batch = [&](int bi) {
        unsigned kb[16];
#pragma unroll
        for (int i = 0; i < 16; ++i) {
            const int j = bi * 16 + i;             // uniform -> scalar loads
            const float4 c = pc[j];
            float dot = fmaf(p.x, c.x, fmaf(p.y, c.y, p.z * c.z));
            float d2  = fmaf(-2.0f, dot, p.w + c.w);   // exactly 0 for self
            kb[i] = (__float_as_uint(d2) & 0xFFFFE000u) | (unsigned)j;
        }
        sort16(kb);
        truncmerge(slot, kb);
        // conservative float upper bound of 16th-best d2 (slot[15] real after 1st batch)
        t_f = fminf(t_f, __uint_as_float((slot[15] & 0xFFFFE000u) + 0x2000u));
    };

    batch(sb0);                                    // seed: 2 local batches (all waves)
    batch(sb0 + 1);

    for (int k = 0; k < 32; ++k) {
        const int bi = wv + (k << 4);
        if (bi == sb0 || bi == sb0 + 1) continue;  // uniform skip (seeded already)
        const float4 lo = bb_lo[bbase + bi];       // uniform s_load
        const float4 hi = bb_hi[bbase + bi];
        float dx = fmaxf(fmaxf(lo.x - p.x, p.x - hi.x), 0.f);
        float dy = fmaxf(fmaxf(lo.y - p.y, p.y - hi.y), 0.f);
        float dz = fmaxf(fmaxf(lo.z - p.z, p.z - hi.z), 0.f);
        float lb = fmaf(dx, dx, fmaf(dy, dy, dz * dz));
        if (__any(fmaf(lb, 0.999f, -1e-5f) < t_f)) batch(bi);
    }

    // drop duplicate seed contributions on waves != 0, restore sortedness
    if (wv != 0) {
        const unsigned jlo = (unsigned)(sb0 << 4), jhi = jlo + 32u;
#pragma unroll
        for (int k = 0; k < 16; ++k) {
            unsigned j = slot[k] & 0x1FFFu;
            bool dup = (j >= jlo) && (j < jhi) && (slot[k] < 0x7F000000u);
            slot[k] = dup ? (0x7F100000u + (unsigned)k) : slot[k];
        }
        sort16(slot);
    }

#pragma unroll
    for (int k = 0; k < 16; ++k) lds_k[wv][k][lane] = slot[k];

    // tree merge 16 -> 1 sorted lists (verified in R3)
    for (int half = 8; half >= 1; half >>= 1) {
        __syncthreads();
        if (wv < half) {
            unsigned a[16], m[16];
#pragma unroll
            for (int k = 0; k < 16; ++k) a[k] = lds_k[wv][k][lane];
#pragma unroll
            for (int k = 0; k < 16; ++k) m[k] = min(a[k], lds_k[wv + half][15 - k][lane]);
#pragma unroll
            for (int st = 8; st >= 1; st >>= 1) {
#pragma unroll
                for (int i = 0; i < 16; ++i) {
                    if ((i & st) == 0) {
                        unsigned lo2 = min(m[i], m[i + st]);
                        unsigned hi2 = max(m[i], m[i + st]);
                        m[i] = lo2; m[i + st] = hi2;
                    }
                }
            }
#pragma unroll
            for (int k = 0; k < 16; ++k) lds_k[wv][k][lane] = m[k];
        }
    }
    __syncthreads();

    if (wv == 0) {
#pragma unroll
        for (int k = 0; k < 16; ++k)
            out_idx[(qbase + lane) * 16 + k] = (int)(lds_k[0][k][lane] & 0x1FFFu) + cloudbase;
    }
}

// brute-force rank (count of smaller scores within cloud), sorted space
__global__ __launch_bounds__(1024) void rank_kernel(const float* __restrict__ s_s,
                                                    int* __restrict__ out_rank) {
    __shared__ int lds_r[16][64];
    const int tid = threadIdx.x, lane = tid & 63;
    const int wv = __builtin_amdgcn_readfirstlane(tid >> 6);
    const int qbase = blockIdx.x * 64;
    const int cloudbase = (qbase >> 13) << 13;
    const float s = s_s[qbase + lane];
    const float* __restrict__ sc = s_s + cloudbase;
    int rank = 0;
    const int j0 = wv * 512;
    for (int jj = 0; jj < 512; jj += 16) {
#pragma unroll
        for (int i = 0; i < 16; ++i) {
            rank += (sc[j0 + jj + i] < s) ? 1 : 0;   // uniform -> scalar loads
        }
    }
    lds_r[wv][lane] = rank;
    __syncthreads();
    if (wv == 0) {
        int rsum = 0;
#pragma unroll
        for (int w = 0; w < 16; ++w) rsum += lds_r[w][lane];
        out_rank[qbase + lane] = rsum;
    }
}

// one thread per (query,k) pair in sorted space; block partials (no global atomics)
__global__ __launch_bounds__(256) void loss_kernel(const float* __restrict__ s_s,
                                                   const float4* __restrict__ pk_s,
                                                   const int* __restrict__ knn,
                                                   const int* __restrict__ rank,
                                                   float* __restrict__ partial) {
    __shared__ float red[4][6];
    const int t = blockIdx.x * 256 + threadIdx.x;
    const int q = t >> 4, k = t & 15;
    const int nb = knn[t];
    const float s  = s_s[q];
    const float sn = s_s[nb];
    const float diff = fabsf(s - sn);
    const float sim = 1.0f - diff;
    const float sg = 1.0f / (1.0f + expf(-2.0f * sim));

    float a_wd = 0.f, a_w = 0.f, a_pos = 0.f, a_neg = 0.f, snk = 0.f;
    if (k < 8) {
        float4 pq = pk_s[q];
        float4 pn = pk_s[nb];
        float dx = pq.x - pn.x, dy = pq.y - pn.y, dz = pq.z - pn.z;
        float d = sqrtf(dx * dx + dy * dy + dz * dz);
        float w = expf(-10.0f * d);
        a_wd = w * diff * diff;
        a_w  = w;
        a_pos = logf(sg + 1e-8f);
        snk = sn;
    } else {
        a_neg = logf(1.0f - sg + 1e-8f);
    }

    float nsum = snk;
#pragma unroll
    for (int off = 1; off < 16; off <<= 1) nsum += __shfl_xor(nsum, off);

    float a_sm = 0.f, a_di = 0.f;
    if (k == 0) {
        float t1 = s - nsum * 0.125f;
        a_sm = t1 * t1;
        float t2 = s - (float)rank[q] * (1.0f / 8191.0f);
        a_di = t2 * t2;
    }

#pragma unroll
    for (int off = 1; off < 64; off <<= 1) {
        a_wd  += __shfl_xor(a_wd, off);
        a_w   += __shfl_xor(a_w, off);
        a_pos += __shfl_xor(a_pos, off);
        a_neg += __shfl_xor(a_neg, off);
        a_sm  += __shfl_xor(a_sm, off);
        a_di  += __shfl_xor(a_di, off);
    }
    const int wv = threadIdx.x >> 6;
    if ((threadIdx.x & 63) == 0) {
        red[wv][0] = a_wd; red[wv][1] = a_w; red[wv][2] = a_pos;
        red[wv][3] = a_neg; red[wv][4] = a_sm; red[wv][5] = a_di;
    }
    __syncthreads();
    if (threadIdx.x < 6) {
        float v = red[0][threadIdx.x] + red[1][threadIdx.x] +
                  red[2][threadIdx.x] + red[3][threadIdx.x];
        partial[threadIdx.x * LOSS_BLOCKS + blockIdx.x] = v;
    }
}

__global__ __launch_bounds__(1024) void fin_kernel(const float* __restrict__ partial,
                                                   float* __restrict__ out) {
    __shared__ float red[16][6];
    const int tid = threadIdx.x;
    float a[6];
#pragma unroll
    for (int term = 0; term < 6; ++term) a[term] = partial[term * LOSS_BLOCKS + tid];
#pragma unroll
    for (int off = 1; off < 64; off <<= 1) {
#pragma unroll
        for (int term = 0; term < 6; ++term) a[term] += __shfl_xor(a[term], off);
    }
    if ((tid & 63) == 0) {
#pragma unroll
        for (int term = 0; term < 6; ++term) red[tid >> 6][term] = a[term];
    }
    __syncthreads();
    if (tid == 0) {
        float acc[6];
#pragma unroll
        for (int term = 0; term < 6; ++term) {
            float v = 0.f;
#pragma unroll
            for (int w = 0; w < 16; ++w) v += red[w][term];
            acc[term] = v;
        }
        float l_loc = acc[0] / fmaxf(acc[1], 1e-8f);
        float l_pos = -acc[2] / (float)(NN * 8);
        float l_neg = -acc[3] / (float)(NN * 8);
        float l_sm  = acc[4] / (float)NN;
        float l_di  = acc[5] / (float)NN;
        out[0] = l_loc + 0.5f * (l_pos + l_neg) + 0.3f * l_di + 0.2f * l_sm;
    }
}

extern "C" void kernel_launch(void* const* d_in, const int* in_sizes, int n_in,
                              void* d_out, int out_size, void* d_ws, size_t ws_size,
                              hipStream_t stream) {
    const float* scores = (const float*)d_in[0];
    const float* coords = (const float*)d_in[1];
    (void)in_sizes; (void)n_in; (void)out_size; (void)ws_size;

    char* ws = (char*)d_ws;
    float*  part  = (float*)(ws + PART_OFF);
    int*    rank  = (int*)(ws + RANK_OFF);
    int*    knn   = (int*)(ws + IDX_OFF);
    float4* pk_s  = (float4*)(ws + PK_OFF);
    float*  s_s   = (float*)(ws + SS_OFF);
    int*    cellid= (int*)(ws + CELLID_OFF);
    int*    cnt   = (int*)(ws + CNT_OFF);
    int*    cursor= (int*)(ws + CUR_OFF);
    float4* bb_lo = (float4*)(ws + BBLO_OFF);
    float4* bb_hi = (float4*)(ws + BBHI_OFF);
    float*  out   = (float*)d_out;

    hipMemsetAsync(cnt, 0, 2 * NCELL * sizeof(int), stream);
    count_kernel<<<64, 256, 0, stream>>>(coords, cellid, cnt);
    scan_kernel<<<1, 1024, 0, stream>>>(cnt, cursor);
    scatter_kernel<<<64, 256, 0, stream>>>(coords, scores, cellid, cursor, pk_s, s_s);
    bbox_kernel<<<4, 256, 0, stream>>>(pk_s, bb_lo, bb_hi);
    knn_kernel<<<256, 1024, 0, stream>>>(pk_s, bb_lo, bb_hi, knn);
    rank_kernel<<<256, 1024, 0, stream>>>(s_s, rank);
    loss_kernel<<<LOSS_BLOCKS, 256, 0, stream>>>(s_s, pk_s, knn, rank, part);
    fin_kernel<<<1, 1024, 0, stream>>>(part, out);
}

// Round 5
// 150.022 us; speedup vs baseline: 3.7456x; 1.0324x over previous
//
#include <hip/hip_runtime.h>
#include <hip/hip_bf16.h>
#include <math.h>

#define BB 2
#define MM 8192
#define NN (BB * MM)
#define NBATCH (NN / 16)      // 1024 batches of 16 sorted points
#define NCELL 4096            // 16^3 morton cells per cloud
#define LOSS_BLOCKS 1024

// ws layout (bytes):
#define PART_OFF   0          // 6 * LOSS_BLOCKS floats = 24576
#define RANK_OFF   24576      // NN ints = 65536
#define IDX_OFF    90112      // NN*16 ints = 1048576
#define PK_OFF     1138688    // NN float4 = 262144
#define SS_OFF     1400832    // NN floats = 65536
#define CELLID_OFF 1466368    // NN ints = 65536
#define CNT_OFF    1531904    // 2*NCELL ints = 32768
#define CUR_OFF    1564672    // 2*NCELL ints = 32768
#define BBLO_OFF   1597440    // NBATCH float4 = 16384
#define BBHI_OFF   1613824    // NBATCH float4 = 16384

__device__ __forceinline__ unsigned mort3(unsigned x, unsigned y, unsigned z) {
    unsigned m = 0;
#pragma unroll
    for (int i = 0; i < 4; ++i) {
        m |= ((x >> i) & 1u) << (3 * i);
        m |= ((y >> i) & 1u) << (3 * i + 1);
        m |= ((z >> i) & 1u) << (3 * i + 2);
    }
    return m;
}

__global__ void count_kernel(const float* __restrict__ coords, int* __restrict__ cellid,
                             int* __restrict__ cnt) {
    int i = blockIdx.x * 256 + threadIdx.x;
    if (i < NN) {
        float x = coords[3 * i], y = coords[3 * i + 1], z = coords[3 * i + 2];
        int cx = min(15, max(0, (int)floorf(x) + 8));
        int cy = min(15, max(0, (int)floorf(y) + 8));
        int cz = min(15, max(0, (int)floorf(z) + 8));
        int cid = (i >> 13) * NCELL + (int)mort3((unsigned)cx, (unsigned)cy, (unsigned)cz);
        cellid[i] = cid;
        atomicAdd(&cnt[cid], 1);
    }
}

// exclusive prefix over 8192 cell counts -> cursor (scatter start positions)
__global__ __launch_bounds__(1024) void scan_kernel(const int* __restrict__ cnt,
                                                    int* __restrict__ cursor) {
    __shared__ int wsum[16];
    const int tid = threadIdx.x, lane = tid & 63, wv = tid >> 6;
    int v[8]; int run = 0;
#pragma unroll
    for (int i = 0; i < 8; ++i) { int t = cnt[tid * 8 + i]; v[i] = run; run += t; }
    int inc = run;
#pragma unroll
    for (int off = 1; off < 64; off <<= 1) {
        int y = __shfl_up(inc, off);
        if (lane >= off) inc += y;
    }
    int laneExcl = inc - run;
    if (lane == 63) wsum[wv] = inc;
    __syncthreads();
    int wbase = 0;
#pragma unroll
    for (int w = 0; w < 16; ++w) wbase += (w < wv) ? wsum[w] : 0;
    const int base = wbase + laneExcl;
#pragma unroll
    for (int i = 0; i < 8; ++i) cursor[tid * 8 + i] = base + v[i];
}

__global__ void scatter_kernel(const float* __restrict__ coords, const float* __restrict__ scores,
                               const int* __restrict__ cellid, int* __restrict__ cursor,
                               float4* __restrict__ pk_s, float* __restrict__ s_s) {
    int i = blockIdx.x * 256 + threadIdx.x;
    if (i < NN) {
        int pos = atomicAdd(&cursor[cellid[i]], 1);
        float x = coords[3 * i], y = coords[3 * i + 1], z = coords[3 * i + 2];
        // MUST match dot ordering in knn_kernel so self-distance is exactly 0.
        float sq = fmaf(x, x, fmaf(y, y, z * z));
        pk_s[pos] = make_float4(x, y, z, sq);
        s_s[pos] = scores[i];
    }
}

__global__ void bbox_kernel(const float4* __restrict__ pk_s, float4* __restrict__ bb_lo,
                            float4* __restrict__ bb_hi) {
    int b = blockIdx.x * 256 + threadIdx.x;
    if (b < NBATCH) {
        float4 c = pk_s[b * 16];
        float lx = c.x, ly = c.y, lz = c.z, hx = c.x, hy = c.y, hz = c.z;
#pragma unroll
        for (int i = 1; i < 16; ++i) {
            c = pk_s[b * 16 + i];
            lx = fminf(lx, c.x); ly = fminf(ly, c.y); lz = fminf(lz, c.z);
            hx = fmaxf(hx, c.x); hy = fmaxf(hy, c.y); hz = fmaxf(hz, c.z);
        }
        bb_lo[b] = make_float4(lx, ly, lz, 0.f);
        bb_hi[b] = make_float4(hx, hy, hz, 0.f);
    }
}

__device__ __forceinline__ void sort16(unsigned (&a)[16]) {
    // Batcher odd-even mergesort, ascending (verified R3/R4, absmax 0)
#pragma unroll
    for (int p2 = 1; p2 < 16; p2 <<= 1) {
#pragma unroll
        for (int k2 = p2; k2 >= 1; k2 >>= 1) {
#pragma unroll
            for (int j2 = k2 % p2; j2 + k2 < 16; j2 += 2 * k2) {
#pragma unroll
                for (int i2 = 0; i2 < k2; ++i2) {
                    if (i2 + j2 + k2 < 16) {
                        if (((i2 + j2) / (2 * p2)) == ((i2 + j2 + k2) / (2 * p2))) {
                            unsigned x = a[i2 + j2], y = a[i2 + j2 + k2];
                            a[i2 + j2]      = min(x, y);
                            a[i2 + j2 + k2] = max(x, y);
                        }
                    }
                }
            }
        }
    }
}

__device__ __forceinline__ void truncmerge(unsigned (&slot)[16], const unsigned (&kb)[16]) {
    // lowest-16 of (sorted slot ∪ sorted kb), result sorted (verified R3/R4)
    unsigned m[16];
#pragma unroll
    for (int k = 0; k < 16; ++k) m[k] = min(slot[k], kb[15 - k]);
#pragma unroll
    for (int st = 8; st >= 1; st >>= 1) {
#pragma unroll
        for (int i = 0; i < 16; ++i) {
            if ((i & st) == 0) {
                unsigned lo = min(m[i], m[i + st]);
                unsigned hi = max(m[i], m[i + st]);
                m[i] = lo; m[i + st] = hi;
            }
        }
    }
#pragma unroll
    for (int k = 0; k < 16; ++k) slot[k] = m[k];
}

// 256 blocks x 1024 threads; block = 64 Morton-consecutive sorted queries.
// Cooperative seed: the 4 local batches are owned by 4 distinct waves
// (residues sb0..sb0+3 mod 16), processed exactly once, unconditionally;
// per-lane 16th-best bounds broadcast via LDS. All other batches bbox-pruned.
// Every batch is processed by exactly one wave -> no dedup needed. Exact.
__global__ __launch_bounds__(1024) void knn_kernel(const float4* __restrict__ pk_s,
                                                   const float4* __restrict__ bb_lo,
                                                   const float4* __restrict__ bb_hi,
                                                   int* __restrict__ out_idx) {
    __shared__ unsigned lds_k[16][16][64];
    __shared__ float lds_t[16][64];
    const int tid = threadIdx.x, lane = tid & 63;
    const int wv = __builtin_amdgcn_readfirstlane(tid >> 6);
    const int qbase = blockIdx.x * 64;
    const int cloudbase = (qbase >> 13) << 13;
    const int q = qbase + lane;
    const float4 p = pk_s[q];
    const int sb0 = (qbase - cloudbase) >> 4;      // first local batch (multiple of 4)
    const float4* __restrict__ pc = pk_s + cloudbase;
    const int bbase = cloudbase >> 4;

    unsigned slot[16];
#pragma unroll
    for (int k = 0; k < 16; ++k) slot[k] = 0x7F000000u + (unsigned)k;  // > any real key
    float t_f = 3.0e38f;

    auto batch = [&](int bi) {
        unsigned kb[16];
#pragma unroll
        for (int i = 0; i < 16; ++i) {
            const int j = bi * 16 + i;             // uniform -> scalar loads
            const float4 c = pc[j];
            float dot = fmaf(p.x, c.x, fmaf(p.y, c.y, p.z * c.z));
            float d2  = fmaf(-2.0f, dot, p.w + c.w);   // exactly 0 for self
            kb[i] = (__float_as_uint(d2) & 0xFFFFE000u) | (unsigned)j;
        }
        sort16(kb);
        truncmerge(slot, kb);
        // conservative upper bound of 16th-best d2 (tie-inclusive: +0x2000)
        t_f = fminf(t_f, __uint_as_float((slot[15] & 0xFFFFE000u) + 0x2000u));
    };

    // cooperative seed: wave owns local batch sb0+(wv-r) if wv in [r, r+4)
    const int r = sb0 & 15;
    const int ownb = (wv >= r && wv < r + 4) ? (sb0 + (wv - r)) : -1;  // uniform
    if (ownb >= 0) batch(ownb);
    lds_t[wv][lane] = t_f;
    __syncthreads();
    float tb = lds_t[0][lane];
#pragma unroll
    for (int w = 1; w < 16; ++w) tb = fminf(tb, lds_t[w][lane]);
    t_f = fminf(t_f, tb);

    // strided scan with bbox lower-bound pruning; prefetch next bbox pair
    float4 lo = bb_lo[bbase + wv];
    float4 hi = bb_hi[bbase + wv];
    for (int k = 0; k < 32; ++k) {
        const int bi = wv + (k << 4);
        float4 lo_n, hi_n;
        if (k + 1 < 32) {                          // uniform branch
            lo_n = bb_lo[bbase + bi + 16];
            hi_n = bb_hi[bbase + bi + 16];
        }
        if (bi != ownb) {                          // uniform skip (seeded already)
            float dx = fmaxf(fmaxf(lo.x - p.x, p.x - hi.x), 0.f);
            float dy = fmaxf(fmaxf(lo.y - p.y, p.y - hi.y), 0.f);
            float dz = fmaxf(fmaxf(lo.z - p.z, p.z - hi.z), 0.f);
            float lb = fmaf(dx, dx, fmaf(dy, dy, dz * dz));
            if (__any(fmaf(lb, 0.999f, -1e-5f) < t_f)) batch(bi);
        }
        lo = lo_n; hi = hi_n;
    }

#pragma unroll
    for (int k = 0; k < 16; ++k) lds_k[wv][k][lane] = slot[k];

    // tree merge 16 -> 1 sorted lists (verified R3/R4)
    for (int half = 8; half >= 1; half >>= 1) {
        __syncthreads();
        if (wv < half) {
            unsigned a[16], m[16];
#pragma unroll
            for (int k = 0; k < 16; ++k) a[k] = lds_k[wv][k][lane];
#pragma unroll
            for (int k = 0; k < 16; ++k) m[k] = min(a[k], lds_k[wv + half][15 - k][lane]);
#pragma unroll
            for (int st = 8; st >= 1; st >>= 1) {
#pragma unroll
                for (int i = 0; i < 16; ++i) {
                    if ((i & st) == 0) {
                        unsigned lo2 = min(m[i], m[i + st]);
                        unsigned hi2 = max(m[i], m[i + st]);
                        m[i] = lo2; m[i + st] = hi2;
                    }
                }
            }
#pragma unroll
            for (int k = 0; k < 16; ++k) lds_k[wv][k][lane] = m[k];
        }
    }
    __syncthreads();

    if (wv == 0) {
#pragma unroll
        for (int k = 0; k < 16; ++k)
            out_idx[(qbase + lane) * 16 + k] = (int)(lds_k[0][k][lane] & 0x1FFFu) + cloudbase;
    }
}

// brute-force rank (count of smaller scores within cloud), sorted space
__global__ __launch_bounds__(1024) void rank_kernel(const float* __restrict__ s_s,
                                                    int* __restrict__ out_rank) {
    __shared__ int lds_r[16][64];
    const int tid = threadIdx.x, lane = tid & 63;
    const int wv = __builtin_amdgcn_readfirstlane(tid >> 6);
    const int qbase = blockIdx.x * 64;
    const int cloudbase = (qbase >> 13) << 13;
    const float s = s_s[qbase + lane];
    const float* __restrict__ sc = s_s + cloudbase;
    int rank = 0;
    const int j0 = wv * 512;
    for (int jj = 0; jj < 512; jj += 16) {
#pragma unroll
        for (int i = 0; i < 16; ++i) {
            rank += (sc[j0 + jj + i] < s) ? 1 : 0;   // uniform -> scalar loads
        }
    }
    lds_r[wv][lane] = rank;
    __syncthreads();
    if (wv == 0) {
        int rsum = 0;
#pragma unroll
        for (int w = 0; w < 16; ++w) rsum += lds_r[w][lane];
        out_rank[qbase + lane] = rsum;
    }
}

// one thread per (query,k) pair in sorted space; block partials (no global atomics)
__global__ __launch_bounds__(256) void loss_kernel(const float* __restrict__ s_s,
                                                   const float4* __restrict__ pk_s,
                                                   const int* __restrict__ knn,
                                                   const int* __restrict__ rank,
                                                   float* __restrict__ partial) {
    __shared__ float red[4][6];
    const int t = blockIdx.x * 256 + threadIdx.x;
    const int q = t >> 4, k = t & 15;
    const int nb = knn[t];
    const float s  = s_s[q];
    const float sn = s_s[nb];
    const float diff = fabsf(s - sn);
    const float sim = 1.0f - diff;
    const float sg = 1.0f / (1.0f + expf(-2.0f * sim));

    float a_wd = 0.f, a_w = 0.f, a_pos = 0.f, a_neg = 0.f, snk = 0.f;
    if (k < 8) {
        float4 pq = pk_s[q];
        float4 pn = pk_s[nb];
        float dx = pq.x - pn.x, dy = pq.y - pn.y, dz = pq.z - pn.z;
        float d = sqrtf(dx * dx + dy * dy + dz * dz);
        float w = expf(-10.0f * d);
        a_wd = w * diff * diff;
        a_w  = w;
        a_pos = logf(sg + 1e-8f);
        snk = sn;
    } else {
        a_neg = logf(1.0f - sg + 1e-8f);
    }

    float nsum = snk;
#pragma unroll
    for (int off = 1; off < 16; off <<= 1) nsum += __shfl_xor(nsum, off);

    float a_sm = 0.f, a_di = 0.f;
    if (k == 0) {
        float t1 = s - nsum * 0.125f;
        a_sm = t1 * t1;
        float t2 = s - (float)rank[q] * (1.0f / 8191.0f);
        a_di = t2 * t2;
    }

#pragma unroll
    for (int off = 1; off < 64; off <<= 1) {
        a_wd  += __shfl_xor(a_wd, off);
        a_w   += __shfl_xor(a_w, off);
        a_pos += __shfl_xor(a_pos, off);
        a_neg += __shfl_xor(a_neg, off);
        a_sm  += __shfl_xor(a_sm, off);
        a_di  += __shfl_xor(a_di, off);
    }
    const int wv = threadIdx.x >> 6;
    if ((threadIdx.x & 63) == 0) {
        red[wv][0] = a_wd; red[wv][1] = a_w; red[wv][2] = a_pos;
        red[wv][3] = a_neg; red[wv][4] = a_sm; red[wv][5] = a_di;
    }
    __syncthreads();
    if (threadIdx.x < 6) {
        float v = red[0][threadIdx.x] + red[1][threadIdx.x] +
                  red[2][threadIdx.x] + red[3][threadIdx.x];
        partial[threadIdx.x * LOSS_BLOCKS + blockIdx.x] = v;
    }
}

__global__ __launch_bounds__(1024) void fin_kernel(const float* __restrict__ partial,
                                                   float* __restrict__ out) {
    __shared__ float red[16][6];
    const int tid = threadIdx.x;
    float a[6];
#pragma unroll
    for (int term = 0; term < 6; ++term) a[term] = partial[term * LOSS_BLOCKS + tid];
#pragma unroll
    for (int off = 1; off < 64; off <<= 1) {
#pragma unroll
        for (int term = 0; term < 6; ++term) a[term] += __shfl_xor(a[term], off);
    }
    if ((tid & 63) == 0) {
#pragma unroll
        for (int term = 0; term < 6; ++term) red[tid >> 6][term] = a[term];
    }
    __syncthreads();
    if (tid == 0) {
        float acc[6];
#pragma unroll
        for (int term = 0; term < 6; ++term) {
            float v = 0.f;
#pragma unroll
            for (int w = 0; w < 16; ++w) v += red[w][term];
            acc[term] = v;
        }
        float l_loc = acc[0] / fmaxf(acc[1], 1e-8f);
        float l_pos = -acc[2] / (float)(NN * 8);
        float l_neg = -acc[3] / (float)(NN * 8);
        float l_sm  = acc[4] / (float)NN;
        float l_di  = acc[5] / (float)NN;
        out[0] = l_loc + 0.5f * (l_pos + l_neg) + 0.3f * l_di + 0.2f * l_sm;
    }
}

extern "C" void kernel_launch(void* const* d_in, const int* in_sizes, int n_in,
                              void* d_out, int out_size, void* d_ws, size_t ws_size,
                              hipStream_t stream) {
    const float* scores = (const float*)d_in[0];
    const float* coords = (const float*)d_in[1];
    (void)in_sizes; (void)n_in; (void)out_size; (void)ws_size;

    char* ws = (char*)d_ws;
    float*  part  = (float*)(ws + PART_OFF);
    int*    rank  = (int*)(ws + RANK_OFF);
    int*    knn   = (int*)(ws + IDX_OFF);
    float4* pk_s  = (float4*)(ws + PK_OFF);
    float*  s_s   = (float*)(ws + SS_OFF);
    int*    cellid= (int*)(ws + CELLID_OFF);
    int*    cnt   = (int*)(ws + CNT_OFF);
    int*    cursor= (int*)(ws + CUR_OFF);
    float4* bb_lo = (float4*)(ws + BBLO_OFF);
    float4* bb_hi = (float4*)(ws + BBHI_OFF);
    float*  out   = (float*)d_out;

    hipMemsetAsync(cnt, 0, 2 * NCELL * sizeof(int), stream);
    count_kernel<<<64, 256, 0, stream>>>(coords, cellid, cnt);
    scan_kernel<<<1, 1024, 0, stream>>>(cnt, cursor);
    scatter_kernel<<<64, 256, 0, stream>>>(coords, scores, cellid, cursor, pk_s, s_s);
    bbox_kernel<<<4, 256, 0, stream>>>(pk_s, bb_lo, bb_hi);
    knn_kernel<<<256, 1024, 0, stream>>>(pk_s, bb_lo, bb_hi, knn);
    rank_kernel<<<256, 1024, 0, stream>>>(s_s, rank);
    loss_kernel<<<LOSS_BLOCKS, 256, 0, stream>>>(s_s, pk_s, knn, rank, part);
    fin_kernel<<<1, 1024, 0, stream>>>(part, out);
}